// Round 4
// baseline (813.731 us; speedup 1.0000x reference)
//
#include <hip/hip_runtime.h>

typedef unsigned short u16;
typedef unsigned int u32;
typedef __attribute__((ext_vector_type(8))) short short8;
typedef __attribute__((ext_vector_type(4))) float f32x4;

__device__ __forceinline__ float b2f(u16 u) {
    return __builtin_bit_cast(float, (u32)u << 16);
}
__device__ __forceinline__ u16 f2b(float f) {   // RNE fp32 -> bf16
    u32 x = __builtin_bit_cast(u32, f);
    x += 0x7fffu + ((x >> 16) & 1u);
    return (u16)(x >> 16);
}

// ---------------- workspace layout (units: floats from ws base) ----------------
#define WS_LPART  0           // 512 floats (per-block loss partials; 256 used)
#define WS_ENORM  512         // 8192
#define WS_ZQSUM  8704        // 4096*128 = 524288 -> ends 532992
#define WS_BETAS  532992      // u16: 5*4096*256 = 2621440 floats -> ends 3154432
#define WS_W0PAD  3154432     // u16: 256*64 = 8192 floats -> ends 3162624
#define WS_DWH    3162624     // u16: 4*256*256 = 131072 floats -> ends 3293696
// bf16 hi/lo codebook split: ALIASES the betas region (vq finishes before betas
// is written on the same stream). Each array: 8192*128 u16 = 524288 floats.
#define WS_VQH    WS_BETAS
#define WS_VQL    (WS_BETAS + 524288)

// ---------------------------------------------------------------- e-norms (fp32)
__global__ __launch_bounds__(64) void enorm_kernel(const float* __restrict__ vq,
                                                   float* __restrict__ enorm) {
    int code = blockIdx.x;            // 8192 = S*K
    int lane = threadIdx.x;
    const float* e = vq + (size_t)code * 128;
    float a = e[lane], b = e[lane + 64];
    float v = a * a + b * b;
    #pragma unroll
    for (int off = 32; off; off >>= 1) v += __shfl_down(v, off);
    if (lane == 0) enorm[code] = v;
}

// ---------------------------------------------------------------- codebook fp32 -> bf16 hi/lo split
__global__ __launch_bounds__(256) void vqsplit_kernel(const float* __restrict__ vq,
                                                      u16* __restrict__ vh,
                                                      u16* __restrict__ vl) {
    int i = blockIdx.x * 256 + threadIdx.x;   // 1048576 = 8192*128
    float v = vq[i];
    u16 h = f2b(v);
    vh[i] = h;
    vl[i] = f2b(v - b2f(h));
}

// ---------------------------------------------------------------- W0 pad 42->64, fp32 -> bf16
__global__ __launch_bounds__(256) void padw0_kernel(const float* __restrict__ W0,
                                                    u16* __restrict__ w0pad) {
    int i = blockIdx.x * 256 + threadIdx.x;   // 16384
    int row = i >> 6, k = i & 63;
    w0pad[i] = (k < 42) ? f2b(W0[row * 42 + k]) : (u16)0;
}

// ---------------------------------------------------------------- dec_Wh fp32 -> bf16
__global__ __launch_bounds__(256) void dwh_kernel(const float* __restrict__ Wh,
                                                  u16* __restrict__ dwh) {
    int i = blockIdx.x * 256 + threadIdx.x;   // 262144
    dwh[i] = f2b(Wh[i]);
}

// ---------------------------------------------------------------- fused residual VQ (MFMA distances)
// 256 blocks x 512 threads (8 waves); block owns 16 batch rows. Split-fp32
// bf16 MFMA distances; 1e-2 near-ties rescored in fp64 -> exact argmin.
__global__ __launch_bounds__(512, 2) void vq_kernel(const int* __restrict__ lidx,
                                                    const float* __restrict__ latents,
                                                    const float* __restrict__ vq,
                                                    const u16* __restrict__ vqh,
                                                    const u16* __restrict__ vql,
                                                    const float* __restrict__ enorm,
                                                    float* __restrict__ zqsum_g,
                                                    float* __restrict__ lpartial) {
    int tid = threadIdx.x;
    int wv = tid >> 6;         // wave 0..7
    int lane = tid & 63;
    int col = lane & 15;       // z-row (B col / D col)
    int g = lane >> 4;         // k-group / D row group
    int urow = tid >> 5;       // state-update row 0..15
    int uc = tid & 31;         // state-update float4 col 0..31

    __shared__ __align__(16) float s_resid[16][132];
    __shared__ __align__(16) float s_zqsum[16][132];
    __shared__ __align__(16) float s_zcur[16][132];
    __shared__ float rd1[32][16], rd2[32][16];
    __shared__ int   ri1[32][16], ri2[32][16];
    __shared__ int   sel[16];
    __shared__ float lossb[8];

    size_t li_u = (size_t)lidx[blockIdx.x * 16 + urow];

    // stage-0 init
    {
        float4 v = ((const float4*)latents)[li_u * 128 + uc];
        *(float4*)&s_resid[urow][uc * 4] = v;
        *(float4*)&s_zcur[urow][uc * 4]  = v;
        float4 z = {0.f, 0.f, 0.f, 0.f};
        *(float4*)&s_zqsum[urow][uc * 4] = z;
    }
    float loss_local = 0.f;
    __syncthreads();

    for (int s = 0; s < 4; ++s) {
        // B fragments: this lane's z-row slice -> bf16 hi/lo, in registers
        short8 bh[4], bl[4];
        #pragma unroll
        for (int kc4 = 0; kc4 < 4; ++kc4) {
            int kk = kc4 * 32 + g * 8;
            float4 z0 = *(const float4*)&s_zcur[col][kk];
            float4 z1 = *(const float4*)&s_zcur[col][kk + 4];
            float zz[8] = {z0.x, z0.y, z0.z, z0.w, z1.x, z1.y, z1.z, z1.w};
            short8 h8, l8;
            #pragma unroll
            for (int j = 0; j < 8; ++j) {
                u16 hb = f2b(zz[j]);
                h8[j] = (short)hb;
                l8[j] = (short)f2b(zz[j] - b2f(hb));
            }
            bh[kc4] = h8; bl[kc4] = l8;
        }

        const u16* baseh = vqh + ((size_t)(s * 2048 + wv * 256 + col)) * 128 + g * 8;
        const u16* basel = vql + ((size_t)(s * 2048 + wv * 256 + col)) * 128 + g * 8;
        const float* enb = enorm + s * 2048 + wv * 256 + g * 4;

        float b1 = 3.4e38f, b2v = 3.4e38f; int i1 = 0, i2 = 0;
        auto top2 = [&](float dv, int kv) {
            if (dv < b1)       { b2v = b1; i2 = i1; b1 = dv; i1 = kv; }
            else if (dv < b2v) { b2v = dv; i2 = kv; }
        };

        for (int tp = 0; tp < 8; ++tp) {
            const u16* phA = baseh + (size_t)tp * 32 * 128;
            const u16* plA = basel + (size_t)tp * 32 * 128;
            short8 ahA[4], alA[4], ahB[4], alB[4];
            #pragma unroll
            for (int kc4 = 0; kc4 < 4; ++kc4) {
                ahA[kc4] = *(const short8*)&phA[kc4 * 32];
                alA[kc4] = *(const short8*)&plA[kc4 * 32];
                ahB[kc4] = *(const short8*)&phA[16 * 128 + kc4 * 32];
                alB[kc4] = *(const short8*)&plA[16 * 128 + kc4 * 32];
            }
            f32x4 accA = {0.f, 0.f, 0.f, 0.f};
            f32x4 accB = {0.f, 0.f, 0.f, 0.f};
            #pragma unroll
            for (int kc4 = 0; kc4 < 4; ++kc4) {
                accA = __builtin_amdgcn_mfma_f32_16x16x32_bf16(ahA[kc4], bh[kc4], accA, 0, 0, 0);
                accB = __builtin_amdgcn_mfma_f32_16x16x32_bf16(ahB[kc4], bh[kc4], accB, 0, 0, 0);
                accA = __builtin_amdgcn_mfma_f32_16x16x32_bf16(ahA[kc4], bl[kc4], accA, 0, 0, 0);
                accB = __builtin_amdgcn_mfma_f32_16x16x32_bf16(ahB[kc4], bl[kc4], accB, 0, 0, 0);
                accA = __builtin_amdgcn_mfma_f32_16x16x32_bf16(alA[kc4], bh[kc4], accA, 0, 0, 0);
                accB = __builtin_amdgcn_mfma_f32_16x16x32_bf16(alB[kc4], bh[kc4], accB, 0, 0, 0);
            }
            float4 enA = *(const float4*)&enb[tp * 32];
            float4 enB = *(const float4*)&enb[tp * 32 + 16];
            int kA = wv * 256 + tp * 32 + g * 4;
            int kB = kA + 16;
            top2(enA.x - 2.f * accA[0], kA + 0);
            top2(enA.y - 2.f * accA[1], kA + 1);
            top2(enA.z - 2.f * accA[2], kA + 2);
            top2(enA.w - 2.f * accA[3], kA + 3);
            top2(enB.x - 2.f * accB[0], kB + 0);
            top2(enB.y - 2.f * accB[1], kB + 1);
            top2(enB.z - 2.f * accB[2], kB + 2);
            top2(enB.w - 2.f * accB[3], kB + 3);
        }
        int slot = wv * 4 + g;
        rd1[slot][col] = b1; rd2[slot][col] = b2v;
        ri1[slot][col] = i1; ri2[slot][col] = i2;
        __syncthreads();

        if (tid < 16) {   // merge 32 top-2 lists for row tid, then exact rescore of near-ties
            float m1 = 3.4e38f, m2 = 3.4e38f; int j1 = 0, j2 = 0;
            for (int sl = 0; sl < 32; ++sl) {
                float d1c = rd1[sl][tid], d2c = rd2[sl][tid];
                int   k1 = ri1[sl][tid], k2 = ri2[sl][tid];
                if (d1c < m1) {
                    float n2; int n2i;
                    if (m1 <= d2c) { n2 = m1; n2i = j1; } else { n2 = d2c; n2i = k2; }
                    m1 = d1c; j1 = k1; m2 = n2; j2 = n2i;
                } else if (d1c < m2) { m2 = d1c; j2 = k1; }
            }
            int jw = j1;
            if (m2 - m1 < 1e-2f) {
                const float* e1p = vq + ((size_t)s * 2048 + j1) * 128;
                const float* e2p = vq + ((size_t)s * 2048 + j2) * 128;
                double t1 = 0.0, t2 = 0.0;
                for (int d = 0; d < 128; ++d) {
                    double z  = (double)s_zcur[tid][d];
                    double e1 = (double)e1p[d], e2 = (double)e2p[d];
                    t1 += e1 * e1 - 2.0 * e1 * z;
                    t2 += e2 * e2 - 2.0 * e2 * z;
                }
                if (t2 < t1 || (t2 == t1 && j2 < j1)) jw = j2;
            }
            sel[tid] = jw;
        }
        __syncthreads();

        // state update, reference rounding order
        {
            int k = sel[urow];
            float4 e = ((const float4*)vq)[((size_t)s * 2048 + k) * 32 + uc];
            int d = uc * 4;
            float4 z4 = *(const float4*)&s_zcur[urow][d];
            float f0 = e.x - z4.x, f1 = e.y - z4.y;
            float f2v = e.z - z4.z, f3 = e.w - z4.w;
            loss_local += f0 * f0 + f1 * f1 + f2v * f2v + f3 * f3;
            float4 zq = *(float4*)&s_zqsum[urow][d];
            zq.x += e.x; zq.y += e.y; zq.z += e.z; zq.w += e.w;
            *(float4*)&s_zqsum[urow][d] = zq;
            if (s < 3) {
                float4 lv = ((const float4*)latents)[li_u * 128 + (size_t)(s + 1) * 32 + uc];
                float4 rs = *(float4*)&s_resid[urow][d];
                rs.x += lv.x; rs.y += lv.y; rs.z += lv.z; rs.w += lv.w;
                *(float4*)&s_resid[urow][d] = rs;
                float4 zcn;
                zcn.x = rs.x - zq.x; zcn.y = rs.y - zq.y;
                zcn.z = rs.z - zq.z; zcn.w = rs.w - zq.w;
                *(float4*)&s_zcur[urow][d] = zcn;
            }
        }
        __syncthreads();
    }

    // write z_q_sum (16 rows x 128, coalesced float4)
    ((float4*)zqsum_g)[((size_t)blockIdx.x * 16 + urow) * 32 + uc] =
        *(const float4*)&s_zqsum[urow][uc * 4];

    // loss partial: reduce across all 512 threads
    #pragma unroll
    for (int off = 32; off; off >>= 1) loss_local += __shfl_down(loss_local, off);
    if (lane == 0) lossb[wv] = loss_local;
    __syncthreads();
    if (tid == 0) {
        float l = 0.f;
        #pragma unroll
        for (int i = 0; i < 8; ++i) l += lossb[i];
        lpartial[blockIdx.x] = l;
    }
}

// ---------------------------------------------------------------- betas (fp32 VALU -> bf16)
__global__ __launch_bounds__(128) void betas_kernel(const float* __restrict__ zqsum,
                                                    const float* __restrict__ mod_W,
                                                    const float* __restrict__ mod_b,
                                                    u16* __restrict__ betas) {
    int bg = blockIdx.x, l = blockIdx.y, t = threadIdx.x;
    __shared__ float zq[16][128];
    for (int u = t; u < 2048; u += 128) ((float*)zq)[u] = zqsum[(size_t)bg * 2048 + u];
    __syncthreads();

    float acc0[16], acc1[16];
    #pragma unroll
    for (int i = 0; i < 16; ++i) { acc0[i] = 0.f; acc1[i] = 0.f; }

    const float4* w0 = (const float4*)(mod_W + ((size_t)l * 256 + t) * 128);
    const float4* w1 = (const float4*)(mod_W + ((size_t)l * 256 + t + 128) * 128);
    #pragma unroll
    for (int c = 0; c < 32; ++c) {
        float4 wa = w0[c], wb = w1[c];
        #pragma unroll
        for (int bb = 0; bb < 16; ++bb) {
            float4 za = *(const float4*)&zq[bb][c * 4];
            acc0[bb] += wa.x * za.x + wa.y * za.y + wa.z * za.z + wa.w * za.w;
            acc1[bb] += wb.x * za.x + wb.y * za.y + wb.z * za.z + wb.w * za.w;
        }
    }
    float bias0 = mod_b[l * 256 + t], bias1 = mod_b[l * 256 + t + 128];
    #pragma unroll
    for (int bb = 0; bb < 16; ++bb) {
        size_t o = ((size_t)l * 4096 + bg * 16 + bb) * 256;
        betas[o + t]       = f2b(acc0[bb] + bias0);
        betas[o + t + 128] = f2b(acc1[bb] + bias1);
    }
}

// ---------------------------------------------------------------- single-buffered MFMA GEMM core
// Single-buffer fragments (regs: 32 frag + 64 acc) so 2 blocks x 8 waves fit at
// <=128 regs/wave -> 4 waves/SIMD. Fully unrolled; compiler pipelines within cap.
template<int KD>
__device__ __forceinline__ void gemm_run(const u16* __restrict__ wl, const int wstride,
                                         const u16* __restrict__ xb, const int colsw,
                                         f32x4 acc[4][4]) {
    #pragma unroll
    for (int it = 0; it < KD / 32; ++it) {
        const int kc = it * 32;
        short8 a[4], bf[4];
        #pragma unroll
        for (int nt = 0; nt < 4; ++nt)
            a[nt] = *(const short8*)&wl[(size_t)nt * 16 * wstride + kc];
        #pragma unroll
        for (int mt = 0; mt < 4; ++mt)
            bf[mt] = *(const short8*)&xb[mt * 16 * 256 + (kc ^ colsw)];
        #pragma unroll
        for (int nt = 0; nt < 4; ++nt)
            #pragma unroll
            for (int mt = 0; mt < 4; ++mt)
                acc[nt][mt] = __builtin_amdgcn_mfma_f32_16x16x32_bf16(
                    a[nt], bf[mt], acc[nt][mt], 0, 0, 0);
    }
}

// ---------------------------------------------------------------- fused MLP (bf16 MFMA)
// 2 images per block (2048 blocks), 512 threads = 8 waves = two 4-wave groups,
// one per image; group wave wv4 covers weight cols [wv4*64, wv4*64+64).
// X = 2 x 64x256 u16 (64 KB) with 16B-granule XOR swizzle -> 2 blocks/CU
// (LDS-limited) = 4 waves/SIMD, matched by the <=128-reg cap from
// launch_bounds(512,4). Halving the block count halves L2 weight traffic, and
// lockstep groups L1-hit each other's weight lines. Epilogue packs bf16 pairs
// with v_cvt_pk_bf16_f32 (RNE, bit-identical to f2b).
__global__ __launch_bounds__(512, 4) void mlp_kernel(const float* __restrict__ coords,
                                                     const u16* __restrict__ w0pad,
                                                     const float* __restrict__ dec_b0,
                                                     const u16* __restrict__ dwh,
                                                     const float* __restrict__ dec_bh,
                                                     const float* __restrict__ last_W,
                                                     const float* __restrict__ last_b,
                                                     const u16* __restrict__ betas,
                                                     float* __restrict__ out) {
    __shared__ __align__(16) u16 X[2 * 64 * 256];
    int b = blockIdx.x;
    int tid = threadIdx.x;
    int lane = tid & 63, wv = tid >> 6;      // wave 0..7
    int wv4 = wv & 3, img = wv >> 2;         // 4-wave group per image
    int q = lane >> 4, r16 = lane & 15;
    int nbase = wv4 * 64;
    int swr = (r16 & 7) << 3;
    int colsw = (q * 8) ^ swr;
    int bimg = b * 2 + img;
    u16* Xi = X + img * 16384;

    // positional encoding: 8 groups = 2 images x 4 roles
    {
        int m = tid & 63, g = tid >> 6;
        int gimg = g >> 2, gg = g & 3;
        int gbi = b * 2 + gimg;
        u16* Xg = X + gimg * 16384;
        auto xput = [&](int mm, int c, u16 val) {
            Xg[mm * 256 + (c ^ ((mm & 7) << 3))] = val;
        };
        float c0 = coords[(((size_t)gbi << 6) + m) * 2 + 0];
        float c1 = coords[(((size_t)gbi << 6) + m) * 2 + 1];
        if (gg == 0) {
            xput(m, 0, f2b(c0)); xput(m, 1, f2b(c1));
            #pragma unroll
            for (int c = 42; c < 64; ++c) xput(m, c, 0);
            #pragma unroll
            for (int f = 0; f < 10; ++f) {
                float pf = 3.14159265358979323846f * (float)(1 << f);
                xput(m, 32 + f, f2b(cosf(c1 * pf)));
            }
        } else if (gg == 1) {
            #pragma unroll
            for (int f = 0; f < 10; ++f) {
                float pf = 3.14159265358979323846f * (float)(1 << f);
                xput(m, 2 + f, f2b(sinf(c0 * pf)));
            }
        } else if (gg == 2) {
            #pragma unroll
            for (int f = 0; f < 10; ++f) {
                float pf = 3.14159265358979323846f * (float)(1 << f);
                xput(m, 12 + f, f2b(sinf(c1 * pf)));
            }
        } else {
            #pragma unroll
            for (int f = 0; f < 10; ++f) {
                float pf = 3.14159265358979323846f * (float)(1 << f);
                xput(m, 22 + f, f2b(cosf(c0 * pf)));
            }
        }
    }
    __syncthreads();

    f32x4 acc[4][4];   // [nt][mt]
    const u16* xb = Xi + r16 * 256;

    auto zero_acc = [&]() {
        #pragma unroll
        for (int nt = 0; nt < 4; ++nt)
            #pragma unroll
            for (int mt = 0; mt < 4; ++mt) {
                f32x4 z = {0.f, 0.f, 0.f, 0.f};
                acc[nt][mt] = z;
            }
    };

    auto epilogue = [&](const float* bias, const u16* beta_l) {
        float bv[4][4];
        #pragma unroll
        for (int nt = 0; nt < 4; ++nt) {
            int n0 = nbase + nt * 16 + q * 4;
            float4 bs = *(const float4*)&bias[n0];
            ushort4 bt = *(const ushort4*)&beta_l[n0];
            bv[nt][0] = bs.x + b2f(bt.x);
            bv[nt][1] = bs.y + b2f(bt.y);
            bv[nt][2] = bs.z + b2f(bt.z);
            bv[nt][3] = bs.w + b2f(bt.w);
        }
        __syncthreads();   // all waves done reading X
        #pragma unroll
        for (int mt = 0; mt < 4; ++mt) {
            int m = mt * 16 + r16;
            #pragma unroll
            for (int nt = 0; nt < 4; ++nt) {
                int n0 = nbase + nt * 16 + q * 4;
                float v0 = fmaxf(acc[nt][mt][0] + bv[nt][0], 0.f);
                float v1 = fmaxf(acc[nt][mt][1] + bv[nt][1], 0.f);
                float v2 = fmaxf(acc[nt][mt][2] + bv[nt][2], 0.f);
                float v3 = fmaxf(acc[nt][mt][3] + bv[nt][3], 0.f);
                uint2 pk;
                asm("v_cvt_pk_bf16_f32 %0, %1, %2" : "=v"(pk.x) : "v"(v0), "v"(v1));
                asm("v_cvt_pk_bf16_f32 %0, %1, %2" : "=v"(pk.y) : "v"(v2), "v"(v3));
                *(uint2*)&Xi[m * 256 + (n0 ^ swr)] = pk;
            }
        }
        __syncthreads();
    };

    zero_acc();
    gemm_run<64>(w0pad + (size_t)(nbase + r16) * 64 + q * 8, 64, xb, colsw, acc);
    epilogue(dec_b0, betas + (size_t)bimg * 256);

    #pragma unroll
    for (int l = 1; l < 5; ++l) {
        zero_acc();
        gemm_run<256>(dwh + (size_t)(l - 1) * 65536 + (size_t)(nbase + r16) * 256 + q * 8,
                      256, xb, colsw, acc);
        epilogue(dec_bh + (size_t)(l - 1) * 256, betas + ((size_t)l * 4096 + bimg) * 256);
    }

    // ---- last layer via MFMA: out[64x3] = X[64x256] @ last_W.T, hi/lo W split.
    // Per image, its 4 waves each handle 16 activation rows (B operand); A rows
    // = the 3 output channels (r16<3), zeros elsewhere. D: col=lane&15 -> act
    // row, reg 0..2 (q==0 lanes) -> channel.
    {
        const u16* xt = Xi + (wv4 * 16 + r16) * 256;
        const float* lwp = last_W + r16 * 256 + q * 8;
        f32x4 tacc = {0.f, 0.f, 0.f, 0.f};
        #pragma unroll
        for (int kc = 0; kc < 256; kc += 32) {
            short8 xf = *(const short8*)&xt[kc ^ colsw];
            short8 wh, wl8;
            if (r16 < 3) {
                float4 wa = *(const float4*)&lwp[kc];
                float4 wb = *(const float4*)&lwp[kc + 4];
                float ww[8] = {wa.x, wa.y, wa.z, wa.w, wb.x, wb.y, wb.z, wb.w};
                #pragma unroll
                for (int j = 0; j < 8; ++j) {
                    u16 hb = f2b(ww[j]);
                    wh[j]  = (short)hb;
                    wl8[j] = (short)f2b(ww[j] - b2f(hb));
                }
            } else {
                #pragma unroll
                for (int j = 0; j < 8; ++j) { wh[j] = 0; wl8[j] = 0; }
            }
            tacc = __builtin_amdgcn_mfma_f32_16x16x32_bf16(wh,  xf, tacc, 0, 0, 0);
            tacc = __builtin_amdgcn_mfma_f32_16x16x32_bf16(wl8, xf, tacc, 0, 0, 0);
        }
        __syncthreads();             // all waves done reading X; reuse as fp32 staging
        float* fbuf = (float*)X;     // 2*192 floats
        if (lane < 16) {             // q==0 lanes hold channels 0..2 in regs 0..2
            int rr = wv4 * 16 + lane;
            fbuf[img * 192 + rr * 3 + 0] = tacc[0] + last_b[0];
            fbuf[img * 192 + rr * 3 + 1] = tacc[1] + last_b[1];
            fbuf[img * 192 + rr * 3 + 2] = tacc[2] + last_b[2];
        }
        __syncthreads();
        if (tid < 384) out[(size_t)b * 384 + tid] = fbuf[tid];
    }
}

// ---------------------------------------------------------------- loss finalize
__global__ __launch_bounds__(64) void finalize_kernel(const float* __restrict__ lpartial,
                                                      float* __restrict__ out) {
    int t = threadIdx.x;
    float s = 0.f;
    for (int i = t; i < 256; i += 64) s += lpartial[i];
    #pragma unroll
    for (int off = 32; off; off >>= 1) s += __shfl_down(s, off);
    if (t == 0) out[786432] = 0.25f * s * (1.f / (4096.f * 128.f));
}

extern "C" void kernel_launch(void* const* d_in, const int* in_sizes, int n_in,
                              void* d_out, int out_size, void* d_ws, size_t ws_size,
                              hipStream_t stream) {
    const float* coords  = (const float*)d_in[0];
    const int*   lidx    = (const int*)d_in[1];
    const float* latents = (const float*)d_in[2];
    const float* vq      = (const float*)d_in[3];
    const float* mod_W   = (const float*)d_in[4];
    const float* mod_b   = (const float*)d_in[5];
    const float* dec_W0  = (const float*)d_in[6];
    const float* dec_b0  = (const float*)d_in[7];
    const float* dec_Wh  = (const float*)d_in[8];
    const float* dec_bh  = (const float*)d_in[9];
    const float* last_W  = (const float*)d_in[10];
    const float* last_b  = (const float*)d_in[11];
    float* out = (float*)d_out;

    float* wsf      = (float*)d_ws;
    float* lpartial = wsf + WS_LPART;
    float* enorm    = wsf + WS_ENORM;
    float* zqsum    = wsf + WS_ZQSUM;
    u16*   betas    = (u16*)(wsf + WS_BETAS);
    u16*   w0pad    = (u16*)(wsf + WS_W0PAD);
    u16*   dwh      = (u16*)(wsf + WS_DWH);
    u16*   vqh      = (u16*)(wsf + WS_VQH);
    u16*   vql      = (u16*)(wsf + WS_VQL);

    enorm_kernel<<<8192, 64, 0, stream>>>(vq, enorm);
    vqsplit_kernel<<<4096, 256, 0, stream>>>(vq, vqh, vql);
    padw0_kernel<<<64, 256, 0, stream>>>(dec_W0, w0pad);
    dwh_kernel<<<1024, 256, 0, stream>>>(dec_Wh, dwh);
    vq_kernel<<<256, 512, 0, stream>>>(lidx, latents, vq, vqh, vql, enorm, zqsum, lpartial);
    betas_kernel<<<dim3(256, 5), 128, 0, stream>>>(zqsum, mod_W, mod_b, betas);
    mlp_kernel<<<2048, 512, 0, stream>>>(coords, w0pad, dec_b0, dwh, dec_bh,
                                         last_W, last_b, betas, out);
    finalize_kernel<<<1, 64, 0, stream>>>(lpartial, out);
}

// Round 5
// 786.523 us; speedup vs baseline: 1.0346x; 1.0346x over previous
//
#include <hip/hip_runtime.h>

typedef unsigned short u16;
typedef unsigned int u32;
typedef __attribute__((ext_vector_type(8))) short short8;
typedef __attribute__((ext_vector_type(4))) float f32x4;

__device__ __forceinline__ float b2f(u16 u) {
    return __builtin_bit_cast(float, (u32)u << 16);
}
__device__ __forceinline__ u16 f2b(float f) {   // RNE fp32 -> bf16
    u32 x = __builtin_bit_cast(u32, f);
    x += 0x7fffu + ((x >> 16) & 1u);
    return (u16)(x >> 16);
}

// ---------------- workspace layout (units: floats from ws base) ----------------
#define WS_LPART  0           // 512 floats (per-block loss partials; 256 used)
#define WS_ENORM  512         // 8192
#define WS_ZQSUM  8704        // 4096*128 = 524288 -> ends 532992
#define WS_BETAS  532992      // u16: 5*4096*256 = 2621440 floats -> ends 3154432
#define WS_W0PAD  3154432     // u16: 256*64 = 8192 floats -> ends 3162624
#define WS_DWH    3162624     // u16: 4*256*256 = 131072 floats -> ends 3293696
// bf16 hi/lo codebook split: ALIASES the betas region (vq finishes before betas
// is written on the same stream). Each array: 8192*128 u16 = 524288 floats.
#define WS_VQH    WS_BETAS
#define WS_VQL    (WS_BETAS + 524288)

// ---------------------------------------------------------------- fused prep
// grid = 2048 (enorm, 4 codes/block) + 4096 (vqsplit) + 64 (padw0) + 1024 (dwh)
__global__ __launch_bounds__(256) void prep_kernel(const float* __restrict__ vq,
                                                   const float* __restrict__ W0,
                                                   const float* __restrict__ Wh,
                                                   float* __restrict__ enorm,
                                                   u16* __restrict__ vh,
                                                   u16* __restrict__ vl,
                                                   u16* __restrict__ w0pad,
                                                   u16* __restrict__ dwh) {
    int bx = blockIdx.x;
    int tid = threadIdx.x;
    if (bx < 2048) {                       // e-norms: wave per code
        int code = bx * 4 + (tid >> 6);
        int lane = tid & 63;
        const float* e = vq + (size_t)code * 128;
        float a = e[lane], b = e[lane + 64];
        float v = a * a + b * b;
        #pragma unroll
        for (int off = 32; off; off >>= 1) v += __shfl_down(v, off);
        if (lane == 0) enorm[code] = v;
    } else if (bx < 2048 + 4096) {         // codebook fp32 -> bf16 hi/lo
        int i = (bx - 2048) * 256 + tid;
        float v = vq[i];
        u16 h = f2b(v);
        vh[i] = h;
        vl[i] = f2b(v - b2f(h));
    } else if (bx < 2048 + 4096 + 64) {    // W0 pad 42->64
        int i = (bx - 6144) * 256 + tid;
        int row = i >> 6, k = i & 63;
        w0pad[i] = (k < 42) ? f2b(W0[row * 42 + k]) : (u16)0;
    } else {                               // dec_Wh -> bf16
        int i = (bx - 6208) * 256 + tid;
        dwh[i] = f2b(Wh[i]);
    }
}

// ---------------------------------------------------------------- fused residual VQ (MFMA distances)
// 256 blocks x 1024 threads (16 waves, 4/SIMD); block owns 16 batch rows.
// Wave wv covers codes [wv*128, wv*128+128) as 8 single 16-code tiles
// (12 accumulating MFMAs each: zh*eh + zh*el + zl*eh). Per-lane top-2 over its
// 32 codes -> 64 lists/row merged by tid<16; 1e-2 near-ties rescored in fp64
// (index tiebreak) -> argmin exact vs fp32 reference.
__global__ __launch_bounds__(1024, 4) void vq_kernel(const int* __restrict__ lidx,
                                                     const float* __restrict__ latents,
                                                     const float* __restrict__ vq,
                                                     const u16* __restrict__ vqh,
                                                     const u16* __restrict__ vql,
                                                     const float* __restrict__ enorm,
                                                     float* __restrict__ zqsum_g,
                                                     float* __restrict__ lpartial) {
    int tid = threadIdx.x;
    int wv = tid >> 6;         // wave 0..15
    int lane = tid & 63;
    int col = lane & 15;       // z-row (B col / D col)
    int g = lane >> 4;         // k-group / D row group
    int urow = tid >> 5;       // state-update row (valid for tid<512)
    int uc = tid & 31;         // state-update float4 col

    __shared__ __align__(16) float s_resid[16][132];
    __shared__ __align__(16) float s_zqsum[16][132];
    __shared__ __align__(16) float s_zcur[16][132];
    __shared__ float rd1[64][16], rd2[64][16];
    __shared__ int   ri1[64][16], ri2[64][16];
    __shared__ int   sel[16];
    __shared__ float lossb[16];

    size_t li_u = 0;
    if (tid < 512) {
        li_u = (size_t)lidx[blockIdx.x * 16 + urow];
        float4 v = ((const float4*)latents)[li_u * 128 + uc];
        *(float4*)&s_resid[urow][uc * 4] = v;
        *(float4*)&s_zcur[urow][uc * 4]  = v;
        float4 z = {0.f, 0.f, 0.f, 0.f};
        *(float4*)&s_zqsum[urow][uc * 4] = z;
    }
    float loss_local = 0.f;
    __syncthreads();

    for (int s = 0; s < 4; ++s) {
        // B fragments: this lane's z-row slice -> bf16 hi/lo, in registers
        short8 bh[4], bl[4];
        #pragma unroll
        for (int kc4 = 0; kc4 < 4; ++kc4) {
            int kk = kc4 * 32 + g * 8;
            float4 z0 = *(const float4*)&s_zcur[col][kk];
            float4 z1 = *(const float4*)&s_zcur[col][kk + 4];
            float zz[8] = {z0.x, z0.y, z0.z, z0.w, z1.x, z1.y, z1.z, z1.w};
            short8 h8, l8;
            #pragma unroll
            for (int j = 0; j < 8; ++j) {
                u16 hb = f2b(zz[j]);
                h8[j] = (short)hb;
                l8[j] = (short)f2b(zz[j] - b2f(hb));
            }
            bh[kc4] = h8; bl[kc4] = l8;
        }

        const u16* baseh = vqh + ((size_t)(s * 2048 + wv * 128 + col)) * 128 + g * 8;
        const u16* basel = vql + ((size_t)(s * 2048 + wv * 128 + col)) * 128 + g * 8;
        const float* enb = enorm + s * 2048 + wv * 128 + g * 4;

        float b1 = 3.4e38f, b2v = 3.4e38f; int i1 = 0, i2 = 0;
        auto top2 = [&](float dv, int kv) {
            if (dv < b1)       { b2v = b1; i2 = i1; b1 = dv; i1 = kv; }
            else if (dv < b2v) { b2v = dv; i2 = kv; }
        };

        #pragma unroll 2
        for (int t = 0; t < 8; ++t) {
            const u16* ph = baseh + (size_t)t * 16 * 128;
            const u16* pl = basel + (size_t)t * 16 * 128;
            short8 ah[4], al[4];
            #pragma unroll
            for (int kc4 = 0; kc4 < 4; ++kc4) {
                ah[kc4] = *(const short8*)&ph[kc4 * 32];
                al[kc4] = *(const short8*)&pl[kc4 * 32];
            }
            f32x4 a = {0.f, 0.f, 0.f, 0.f};
            #pragma unroll
            for (int kc4 = 0; kc4 < 4; ++kc4) {
                a = __builtin_amdgcn_mfma_f32_16x16x32_bf16(ah[kc4], bh[kc4], a, 0, 0, 0);
                a = __builtin_amdgcn_mfma_f32_16x16x32_bf16(ah[kc4], bl[kc4], a, 0, 0, 0);
                a = __builtin_amdgcn_mfma_f32_16x16x32_bf16(al[kc4], bh[kc4], a, 0, 0, 0);
            }
            float4 en = *(const float4*)&enb[t * 16];
            int kT = wv * 128 + t * 16 + g * 4;
            top2(en.x - 2.f * a[0], kT + 0);
            top2(en.y - 2.f * a[1], kT + 1);
            top2(en.z - 2.f * a[2], kT + 2);
            top2(en.w - 2.f * a[3], kT + 3);
        }
        int slot = wv * 4 + g;
        rd1[slot][col] = b1; rd2[slot][col] = b2v;
        ri1[slot][col] = i1; ri2[slot][col] = i2;
        __syncthreads();

        if (tid < 16) {   // merge 64 top-2 lists for row tid, then exact rescore of near-ties
            float m1 = 3.4e38f, m2 = 3.4e38f; int j1 = 0, j2 = 0;
            for (int sl = 0; sl < 64; ++sl) {
                float d1c = rd1[sl][tid], d2c = rd2[sl][tid];
                int   k1 = ri1[sl][tid], k2 = ri2[sl][tid];
                if (d1c < m1) {
                    float n2; int n2i;
                    if (m1 <= d2c) { n2 = m1; n2i = j1; } else { n2 = d2c; n2i = k2; }
                    m1 = d1c; j1 = k1; m2 = n2; j2 = n2i;
                } else if (d1c < m2) { m2 = d1c; j2 = k1; }
            }
            int jw = j1;
            if (m2 - m1 < 1e-2f) {
                const float* e1p = vq + ((size_t)s * 2048 + j1) * 128;
                const float* e2p = vq + ((size_t)s * 2048 + j2) * 128;
                double t1 = 0.0, t2 = 0.0;
                for (int d = 0; d < 128; ++d) {
                    double z  = (double)s_zcur[tid][d];
                    double e1 = (double)e1p[d], e2 = (double)e2p[d];
                    t1 += e1 * e1 - 2.0 * e1 * z;
                    t2 += e2 * e2 - 2.0 * e2 * z;
                }
                if (t2 < t1 || (t2 == t1 && j2 < j1)) jw = j2;
            }
            sel[tid] = jw;
        }
        __syncthreads();

        // state update, reference rounding order (tid<512 only)
        if (tid < 512) {
            int k = sel[urow];
            float4 e = ((const float4*)vq)[((size_t)s * 2048 + k) * 32 + uc];
            int d = uc * 4;
            float4 z4 = *(const float4*)&s_zcur[urow][d];
            float f0 = e.x - z4.x, f1 = e.y - z4.y;
            float f2v = e.z - z4.z, f3 = e.w - z4.w;
            loss_local += f0 * f0 + f1 * f1 + f2v * f2v + f3 * f3;
            float4 zq = *(float4*)&s_zqsum[urow][d];
            zq.x += e.x; zq.y += e.y; zq.z += e.z; zq.w += e.w;
            *(float4*)&s_zqsum[urow][d] = zq;
            if (s < 3) {
                float4 lv = ((const float4*)latents)[li_u * 128 + (size_t)(s + 1) * 32 + uc];
                float4 rs = *(float4*)&s_resid[urow][d];
                rs.x += lv.x; rs.y += lv.y; rs.z += lv.z; rs.w += lv.w;
                *(float4*)&s_resid[urow][d] = rs;
                float4 zcn;
                zcn.x = rs.x - zq.x; zcn.y = rs.y - zq.y;
                zcn.z = rs.z - zq.z; zcn.w = rs.w - zq.w;
                *(float4*)&s_zcur[urow][d] = zcn;
            }
        }
        __syncthreads();
    }

    // write z_q_sum (16 rows x 128, coalesced float4)
    if (tid < 512)
        ((float4*)zqsum_g)[((size_t)blockIdx.x * 16 + urow) * 32 + uc] =
            *(const float4*)&s_zqsum[urow][uc * 4];

    // loss partial: waves 8..15 contribute 0
    #pragma unroll
    for (int off = 32; off; off >>= 1) loss_local += __shfl_down(loss_local, off);
    if (lane == 0) lossb[wv] = loss_local;
    __syncthreads();
    if (tid == 0) {
        float l = 0.f;
        #pragma unroll
        for (int i = 0; i < 16; ++i) l += lossb[i];
        lpartial[blockIdx.x] = l;
    }
}

// ---------------------------------------------------------------- betas (fp32 VALU -> bf16)
__global__ __launch_bounds__(128) void betas_kernel(const float* __restrict__ zqsum,
                                                    const float* __restrict__ mod_W,
                                                    const float* __restrict__ mod_b,
                                                    u16* __restrict__ betas) {
    int bg = blockIdx.x, l = blockIdx.y, t = threadIdx.x;
    __shared__ float zq[16][128];
    for (int u = t; u < 2048; u += 128) ((float*)zq)[u] = zqsum[(size_t)bg * 2048 + u];
    __syncthreads();

    float acc0[16], acc1[16];
    #pragma unroll
    for (int i = 0; i < 16; ++i) { acc0[i] = 0.f; acc1[i] = 0.f; }

    const float4* w0 = (const float4*)(mod_W + ((size_t)l * 256 + t) * 128);
    const float4* w1 = (const float4*)(mod_W + ((size_t)l * 256 + t + 128) * 128);
    #pragma unroll
    for (int c = 0; c < 32; ++c) {
        float4 wa = w0[c], wb = w1[c];
        #pragma unroll
        for (int bb = 0; bb < 16; ++bb) {
            float4 za = *(const float4*)&zq[bb][c * 4];
            acc0[bb] += wa.x * za.x + wa.y * za.y + wa.z * za.z + wa.w * za.w;
            acc1[bb] += wb.x * za.x + wb.y * za.y + wb.z * za.z + wb.w * za.w;
        }
    }
    float bias0 = mod_b[l * 256 + t], bias1 = mod_b[l * 256 + t + 128];
    #pragma unroll
    for (int bb = 0; bb < 16; ++bb) {
        size_t o = ((size_t)l * 4096 + bg * 16 + bb) * 256;
        betas[o + t]       = f2b(acc0[bb] + bias0);
        betas[o + t + 128] = f2b(acc1[bb] + bias1);
    }
}

// ---------------------------------------------------------------- MFMA GEMM core (2 col-tiles/wave)
// Single-buffered, fully unrolled; base regs ~56 (acc 32 + frags 24), leaving
// headroom under the 128-reg cap for compiler pipelining without spill.
template<int KD>
__device__ __forceinline__ void gemm_run(const u16* __restrict__ wl, const int wstride,
                                         const u16* __restrict__ xb, const int colsw,
                                         f32x4 acc[2][4]) {
    #pragma unroll
    for (int it = 0; it < KD / 32; ++it) {
        const int kc = it * 32;
        short8 a[2], bf[4];
        #pragma unroll
        for (int nt = 0; nt < 2; ++nt)
            a[nt] = *(const short8*)&wl[(size_t)nt * 16 * wstride + kc];
        #pragma unroll
        for (int mt = 0; mt < 4; ++mt)
            bf[mt] = *(const short8*)&xb[mt * 16 * 256 + (kc ^ colsw)];
        #pragma unroll
        for (int nt = 0; nt < 2; ++nt)
            #pragma unroll
            for (int mt = 0; mt < 4; ++mt)
                acc[nt][mt] = __builtin_amdgcn_mfma_f32_16x16x32_bf16(
                    a[nt], bf[mt], acc[nt][mt], 0, 0, 0);
    }
}

// ---------------------------------------------------------------- fused MLP (bf16 MFMA)
// one block per image (4096 blocks), 512 threads = 8 waves; wave wv covers
// weight cols [wv*32, wv*32+32) (acc = 2x4 tiles = 32 AGPR). X = 64x256 u16
// (32 KB) with 16B-granule XOR swizzle. (512,4): 2 blocks/CU -> 16 waves/CU,
// reg cap 128 with ~70 used -> no spill (round-4 spilled because acc was 64).
__global__ __launch_bounds__(512, 4) void mlp_kernel(const float* __restrict__ coords,
                                                     const u16* __restrict__ w0pad,
                                                     const float* __restrict__ dec_b0,
                                                     const u16* __restrict__ dwh,
                                                     const float* __restrict__ dec_bh,
                                                     const float* __restrict__ last_W,
                                                     const float* __restrict__ last_b,
                                                     const u16* __restrict__ betas,
                                                     float* __restrict__ out) {
    __shared__ __align__(16) u16 X[64 * 256];
    int b = blockIdx.x;
    int tid = threadIdx.x;
    int lane = tid & 63, wv = tid >> 6;      // wave 0..7
    int q = lane >> 4, r16 = lane & 15;
    int nbase = wv * 32;
    int swr = (r16 & 7) << 3;
    int colsw = (q * 8) ^ swr;

    // positional encoding: roles 0..3 (waves 4..7 idle here; trivial cost)
    {
        int m = tid & 63, g = tid >> 6;
        auto xput = [&](int mm, int c, u16 val) {
            X[mm * 256 + (c ^ ((mm & 7) << 3))] = val;
        };
        if (g < 4) {
            float c0 = coords[(((size_t)b << 6) + m) * 2 + 0];
            float c1 = coords[(((size_t)b << 6) + m) * 2 + 1];
            if (g == 0) {
                xput(m, 0, f2b(c0)); xput(m, 1, f2b(c1));
                #pragma unroll
                for (int c = 42; c < 64; ++c) xput(m, c, 0);
                #pragma unroll
                for (int f = 0; f < 10; ++f) {
                    float pf = 3.14159265358979323846f * (float)(1 << f);
                    xput(m, 32 + f, f2b(cosf(c1 * pf)));
                }
            } else if (g == 1) {
                #pragma unroll
                for (int f = 0; f < 10; ++f) {
                    float pf = 3.14159265358979323846f * (float)(1 << f);
                    xput(m, 2 + f, f2b(sinf(c0 * pf)));
                }
            } else if (g == 2) {
                #pragma unroll
                for (int f = 0; f < 10; ++f) {
                    float pf = 3.14159265358979323846f * (float)(1 << f);
                    xput(m, 12 + f, f2b(sinf(c1 * pf)));
                }
            } else {
                #pragma unroll
                for (int f = 0; f < 10; ++f) {
                    float pf = 3.14159265358979323846f * (float)(1 << f);
                    xput(m, 22 + f, f2b(cosf(c0 * pf)));
                }
            }
        }
    }
    __syncthreads();

    f32x4 acc[2][4];   // [nt][mt]
    const u16* xb = X + r16 * 256;

    auto zero_acc = [&]() {
        #pragma unroll
        for (int nt = 0; nt < 2; ++nt)
            #pragma unroll
            for (int mt = 0; mt < 4; ++mt) {
                f32x4 z = {0.f, 0.f, 0.f, 0.f};
                acc[nt][mt] = z;
            }
    };

    auto epilogue = [&](const float* bias, const u16* beta_l) {
        float bv[2][4];
        #pragma unroll
        for (int nt = 0; nt < 2; ++nt) {
            int n0 = nbase + nt * 16 + q * 4;
            float4 bs = *(const float4*)&bias[n0];
            ushort4 bt = *(const ushort4*)&beta_l[n0];
            bv[nt][0] = bs.x + b2f(bt.x);
            bv[nt][1] = bs.y + b2f(bt.y);
            bv[nt][2] = bs.z + b2f(bt.z);
            bv[nt][3] = bs.w + b2f(bt.w);
        }
        __syncthreads();   // all waves done reading X
        #pragma unroll
        for (int mt = 0; mt < 4; ++mt) {
            int m = mt * 16 + r16;
            #pragma unroll
            for (int nt = 0; nt < 2; ++nt) {
                int n0 = nbase + nt * 16 + q * 4;
                float v0 = fmaxf(acc[nt][mt][0] + bv[nt][0], 0.f);
                float v1 = fmaxf(acc[nt][mt][1] + bv[nt][1], 0.f);
                float v2 = fmaxf(acc[nt][mt][2] + bv[nt][2], 0.f);
                float v3 = fmaxf(acc[nt][mt][3] + bv[nt][3], 0.f);
                uint2 pk;
                asm("v_cvt_pk_bf16_f32 %0, %1, %2" : "=v"(pk.x) : "v"(v0), "v"(v1));
                asm("v_cvt_pk_bf16_f32 %0, %1, %2" : "=v"(pk.y) : "v"(v2), "v"(v3));
                *(uint2*)&X[m * 256 + (n0 ^ swr)] = pk;
            }
        }
        __syncthreads();
    };

    zero_acc();
    gemm_run<64>(w0pad + (size_t)(nbase + r16) * 64 + q * 8, 64, xb, colsw, acc);
    epilogue(dec_b0, betas + (size_t)b * 256);

    #pragma unroll
    for (int l = 1; l < 5; ++l) {
        zero_acc();
        gemm_run<256>(dwh + (size_t)(l - 1) * 65536 + (size_t)(nbase + r16) * 256 + q * 8,
                      256, xb, colsw, acc);
        epilogue(dec_bh + (size_t)(l - 1) * 256, betas + ((size_t)l * 4096 + b) * 256);
    }

    // ---- last layer via MFMA (waves 0..3): out[64x3] = X @ last_W.T, hi/lo split
    f32x4 tacc = {0.f, 0.f, 0.f, 0.f};
    if (wv < 4) {
        const u16* xt = X + (wv * 16 + r16) * 256;
        const float* lwp = last_W + r16 * 256 + q * 8;
        #pragma unroll
        for (int kc = 0; kc < 256; kc += 32) {
            short8 xf = *(const short8*)&xt[kc ^ colsw];
            short8 wh, wl8;
            if (r16 < 3) {
                float4 wa = *(const float4*)&lwp[kc];
                float4 wb = *(const float4*)&lwp[kc + 4];
                float ww[8] = {wa.x, wa.y, wa.z, wa.w, wb.x, wb.y, wb.z, wb.w};
                #pragma unroll
                for (int j = 0; j < 8; ++j) {
                    u16 hb = f2b(ww[j]);
                    wh[j]  = (short)hb;
                    wl8[j] = (short)f2b(ww[j] - b2f(hb));
                }
            } else {
                #pragma unroll
                for (int j = 0; j < 8; ++j) { wh[j] = 0; wl8[j] = 0; }
            }
            tacc = __builtin_amdgcn_mfma_f32_16x16x32_bf16(wh,  xf, tacc, 0, 0, 0);
            tacc = __builtin_amdgcn_mfma_f32_16x16x32_bf16(wl8, xf, tacc, 0, 0, 0);
        }
    }
    __syncthreads();             // X free; reuse as fp32 staging
    {
        float* fbuf = (float*)X;
        if (wv < 4 && lane < 16) {   // q==0 lanes hold channels 0..2 in regs 0..2
            int rr = wv * 16 + lane;
            fbuf[rr * 3 + 0] = tacc[0] + last_b[0];
            fbuf[rr * 3 + 1] = tacc[1] + last_b[1];
            fbuf[rr * 3 + 2] = tacc[2] + last_b[2];
        }
        __syncthreads();
        if (tid < 192) out[(size_t)b * 192 + tid] = fbuf[tid];
    }
}

// ---------------------------------------------------------------- loss finalize
__global__ __launch_bounds__(64) void finalize_kernel(const float* __restrict__ lpartial,
                                                      float* __restrict__ out) {
    int t = threadIdx.x;
    float s = 0.f;
    for (int i = t; i < 256; i += 64) s += lpartial[i];
    #pragma unroll
    for (int off = 32; off; off >>= 1) s += __shfl_down(s, off);
    if (t == 0) out[786432] = 0.25f * s * (1.f / (4096.f * 128.f));
}

extern "C" void kernel_launch(void* const* d_in, const int* in_sizes, int n_in,
                              void* d_out, int out_size, void* d_ws, size_t ws_size,
                              hipStream_t stream) {
    const float* coords  = (const float*)d_in[0];
    const int*   lidx    = (const int*)d_in[1];
    const float* latents = (const float*)d_in[2];
    const float* vq      = (const float*)d_in[3];
    const float* mod_W   = (const float*)d_in[4];
    const float* mod_b   = (const float*)d_in[5];
    const float* dec_W0  = (const float*)d_in[6];
    const float* dec_b0  = (const float*)d_in[7];
    const float* dec_Wh  = (const float*)d_in[8];
    const float* dec_bh  = (const float*)d_in[9];
    const float* last_W  = (const float*)d_in[10];
    const float* last_b  = (const float*)d_in[11];
    float* out = (float*)d_out;

    float* wsf      = (float*)d_ws;
    float* lpartial = wsf + WS_LPART;
    float* enorm    = wsf + WS_ENORM;
    float* zqsum    = wsf + WS_ZQSUM;
    u16*   betas    = (u16*)(wsf + WS_BETAS);
    u16*   w0pad    = (u16*)(wsf + WS_W0PAD);
    u16*   dwh      = (u16*)(wsf + WS_DWH);
    u16*   vqh      = (u16*)(wsf + WS_VQH);
    u16*   vql      = (u16*)(wsf + WS_VQL);

    prep_kernel<<<7232, 256, 0, stream>>>(vq, dec_W0, dec_Wh, enorm, vqh, vql, w0pad, dwh);
    vq_kernel<<<256, 1024, 0, stream>>>(lidx, latents, vq, vqh, vql, enorm, zqsum, lpartial);
    betas_kernel<<<dim3(256, 5), 128, 0, stream>>>(zqsum, mod_W, mod_b, betas);
    mlp_kernel<<<4096, 512, 0, stream>>>(coords, w0pad, dec_b0, dwh, dec_bh,
                                         last_W, last_b, betas, out);
    finalize_kernel<<<1, 64, 0, stream>>>(lpartial, out);
}